// Round 11
// baseline (181.895 us; speedup 1.0000x reference)
//
#include <hip/hip_runtime.h>
#include <math.h>
#include <stdint.h>

#define NN 8192
#define HID 1024
#define PROJ 128

constexpr float INV_T = 1.0f / 0.07f;
constexpr float LN_EPS = 1e-12f;
// exp((d-m)/T) = exp2((d-m)*CC)
constexpr float CC = 14.285714285714286f * 1.4426950408889634f;

typedef __bf16 bf16x8 __attribute__((ext_vector_type(8)));
typedef float f32x4 __attribute__((ext_vector_type(4)));

#define EXP2(x) __builtin_amdgcn_exp2f(x)

#define GLD16(g, l)                                                     \
  __builtin_amdgcn_global_load_lds(                                     \
      (const __attribute__((address_space(1))) uint32_t*)(g),           \
      (__attribute__((address_space(3))) uint32_t*)(l), 16, 0, 0)

__device__ __forceinline__ uint16_t f2bf(float f) {
  union { float f; uint32_t u; } c; c.f = f;
  uint32_t r = (c.u + 0x7FFFu + ((c.u >> 16) & 1u)) >> 16;
  return (uint16_t)r;
}

// gelu(v) ~= v * sigmoid(2u), u = 0.79788456(v + 0.044715 v^3)
__device__ __forceinline__ float gelu_f(float v) {
  float w = v * v;
  float u = v * fmaf(w, 0.0356774081f, 0.7978845608f);
  float e = EXP2(u * -2.8853900818f);
  return v * __builtin_amdgcn_rcpf(1.0f + e);
}

// ---- k_prep: fused conv(x->bf16) + t1(dense_w^T) + t2(dec_w^T * gamma) ----
__global__ __launch_bounds__(256) void k_prep(
    const float* __restrict__ x, uint16_t* __restrict__ xb,
    const float* __restrict__ dw, uint16_t* __restrict__ wt,
    const float* __restrict__ decw, const float* __restrict__ gamma,
    const float* __restrict__ beta, uint16_t* __restrict__ wt2,
    float* __restrict__ sums, float* __restrict__ c_part,
    float* __restrict__ accum) {
  __shared__ __align__(16) char sm[8448];
  const int b = blockIdx.x, t = threadIdx.x;
  if (b < 8192) {
    if (b < 64) sums[b * 256 + t] = 0.f;            // sum[8192]|sumsq[8192]
    else if (b == 64 && t < 2) accum[t] = 0.f;      // accum, ticket
    int i = (b * 256 + t) * 4;
    float4 v = *(const float4*)(x + i);
    ushort4 o;
    o.x = f2bf(v.x); o.y = f2bf(v.y); o.z = f2bf(v.z); o.w = f2bf(v.w);
    *(ushort4*)(xb + i) = o;
  } else if (b < 9216) {
    uint16_t (*tt)[33] = (uint16_t(*)[33])sm;
    const int lb = b - 8192;
    const int cb = (lb & 31) * 32, rb = (lb >> 5) * 32;
    const int tr = t >> 3, tc4 = (t & 7) * 4;
    float4 v = *(const float4*)(dw + (size_t)(rb + tr) * HID + cb + tc4);
    tt[tc4 + 0][tr] = f2bf(v.x);
    tt[tc4 + 1][tr] = f2bf(v.y);
    tt[tc4 + 2][tr] = f2bf(v.z);
    tt[tc4 + 3][tr] = f2bf(v.w);
    __syncthreads();
    const int oc = t >> 3, or4 = (t & 7) * 4;
    ushort4 o;
    o.x = tt[oc][or4 + 0]; o.y = tt[oc][or4 + 1];
    o.z = tt[oc][or4 + 2]; o.w = tt[oc][or4 + 3];
    *(ushort4*)(wt + (size_t)(cb + oc) * HID + rb + or4) = o;
  } else {
    float (*tg)[33] = (float(*)[33])sm;
    float (*tb)[33] = (float(*)[33])(sm + 4224);
    const int lb = b - 9216;
    const int cb = (lb & 3) * 32, rb = (lb >> 2) * 32;
    const int tr = t >> 3, tc4 = (t & 7) * 4;
    const float g = gamma[rb + tr], be = beta[rb + tr];
    float4 v = *(const float4*)(decw + (size_t)(rb + tr) * PROJ + cb + tc4);
    tg[tc4 + 0][tr] = g * v.x;  tb[tc4 + 0][tr] = be * v.x;
    tg[tc4 + 1][tr] = g * v.y;  tb[tc4 + 1][tr] = be * v.y;
    tg[tc4 + 2][tr] = g * v.z;  tb[tc4 + 2][tr] = be * v.z;
    tg[tc4 + 3][tr] = g * v.w;  tb[tc4 + 3][tr] = be * v.w;
    __syncthreads();
    const int oc = t >> 3, or4 = (t & 7) * 4;
    ushort4 o;
    o.x = f2bf(tg[oc][or4 + 0]); o.y = f2bf(tg[oc][or4 + 1]);
    o.z = f2bf(tg[oc][or4 + 2]); o.w = f2bf(tg[oc][or4 + 3]);
    *(ushort4*)(wt2 + (size_t)(cb + oc) * HID + rb + or4) = o;
    if (t < 32) {
      float sc = 0.f, se = 0.f;
#pragma unroll
      for (int d = 0; d < 32; ++d) { sc += tg[t][d]; se += tb[t][d]; }
      c_part[(rb >> 5) * 128 + cb + t] = sc;            // c partial
      c_part[4096 + (rb >> 5) * 128 + cb + t] = se;     // e partial
    }
  }
}

// -------- GEMM1: h = gelu(x@W+b) bf16, + per-row sum/sumsq atomics --------
// 128x128 tile, BK=64 (32 MFMA per barrier: amortizes the latency-bound
// barrier cost at 2 blocks/CU), LDS dbuf 2x32KB, source-side XOR swizzle.
// grid (64, 8): linear%8 = bm%8 -> bn-blocks of one bm share an XCD.
__global__ __launch_bounds__(256) void k_gemm1(
    const uint16_t* __restrict__ Ab, const uint16_t* __restrict__ Bt,
    const float* __restrict__ bias, uint16_t* __restrict__ Hout,
    float* __restrict__ sums) {
  __shared__ __align__(16) uint16_t As[2][128 * 64];  // [buf][hh][row][32k]
  __shared__ __align__(16) uint16_t Bs[2][128 * 64];
  const int tid = threadIdx.x;
  const int bm = blockIdx.x * 128, bn = blockIdx.y * 128;
  const int wave = tid >> 6, lane = tid & 63;
  const int wx = wave & 1, wy = wave >> 1;
  const int col = lane & 15, quad = lane >> 4;
  const int csw = (col >> 1) & 3;   // read-side chunk swizzle
  f32x4 acc[4][4] = {};
  const char* Abase = (const char*)Ab;
  const char* Bbase = (const char*)Bt;

#define G1STAGE(k0v, bufv)                                                   \
  {                                                                          \
    _Pragma("unroll") for (int l = 0; l < 4; ++l) {                          \
      int off = tid * 16 + l * 4096;                                         \
      int hh = off >> 13, row = (off >> 6) & 127;                            \
      int sp = ((off >> 4) & 3) ^ ((row >> 1) & 3);                          \
      GLD16(Abase + ((size_t)(bm + row) * HID + (k0v) + hh * 32) * 2 +       \
                sp * 16,                                                     \
            (char*)&As[bufv][0] + off);                                      \
    }                                                                        \
    _Pragma("unroll") for (int l = 0; l < 4; ++l) {                          \
      int off = tid * 16 + l * 4096;                                         \
      int hh = off >> 13, row = (off >> 6) & 127;                            \
      int sp = ((off >> 4) & 3) ^ ((row >> 1) & 3);                          \
      GLD16(Bbase + ((size_t)(bn + row) * HID + (k0v) + hh * 32) * 2 +       \
                sp * 16,                                                     \
            (char*)&Bs[bufv][0] + off);                                      \
    }                                                                        \
  }

  G1STAGE(0, 0);
  for (int it = 0; it < 16; ++it) {
    const int buf = it & 1;
    __syncthreads();           // staging for panel `it` landed
    if (it < 15) G1STAGE((it + 1) * 64, buf ^ 1);
#pragma unroll
    for (int hh = 0; hh < 2; ++hh) {
      bf16x8 a[4], b[4];
#pragma unroll
      for (int mt = 0; mt < 4; ++mt)
        a[mt] = *(const bf16x8*)&As[buf][hh * 4096 +
                                         (wy * 64 + mt * 16 + col) * 32 +
                                         (quad ^ csw) * 8];
#pragma unroll
      for (int nt = 0; nt < 4; ++nt)
        b[nt] = *(const bf16x8*)&Bs[buf][hh * 4096 +
                                         (wx * 64 + nt * 16 + col) * 32 +
                                         (quad ^ csw) * 8];
#pragma unroll
      for (int mt = 0; mt < 4; ++mt)
#pragma unroll
        for (int nt = 0; nt < 4; ++nt)
          acc[mt][nt] = __builtin_amdgcn_mfma_f32_16x16x32_bf16(
              a[mt], b[nt], acc[mt][nt], 0, 0, 0);
    }
  }
#undef G1STAGE
  float rsum[4][4] = {}, rsq[4][4] = {};
#pragma unroll
  for (int nt = 0; nt < 4; ++nt) {
    int gj = bn + wx * 64 + nt * 16 + col;
    float bv = bias[gj];
#pragma unroll
    for (int mt = 0; mt < 4; ++mt)
#pragma unroll
      for (int r = 0; r < 4; ++r) {
        int gi = bm + wy * 64 + mt * 16 + quad * 4 + r;
        float gl = gelu_f(acc[mt][nt][r] + bv);
        Hout[(size_t)gi * HID + gj] = f2bf(gl);
        rsum[mt][r] += gl;
        rsq[mt][r] = fmaf(gl, gl, rsq[mt][r]);
      }
  }
#pragma unroll
  for (int mt = 0; mt < 4; ++mt)
#pragma unroll
    for (int r = 0; r < 4; ++r) {
      float s1 = rsum[mt][r], s2 = rsq[mt][r];
#pragma unroll
      for (int off = 1; off < 16; off <<= 1) {
        s1 += __shfl_xor(s1, off, 64);
        s2 += __shfl_xor(s2, off, 64);
      }
      if (col == 0) {
        int gi = bm + wy * 64 + mt * 16 + quad * 4 + r;
        atomicAdd(&sums[gi], s1);
        atomicAdd(&sums[NN + gi], s2);
      }
    }
}

// --- GEMM2 with LN folded: z = r*(h@Wg) - r*mu*c + e + dec_b, bf16 out ----
// 32x128 tile, BK=64 (16 iters), dbuf single-barrier, same XOR swizzle.
__global__ __launch_bounds__(256) void k_gemm2(
    const uint16_t* __restrict__ Hb, const uint16_t* __restrict__ Wt2,
    const float* __restrict__ bd, const float* __restrict__ sums,
    const float* __restrict__ c_part, uint16_t* __restrict__ Z) {
  __shared__ __align__(16) uint16_t As2[2][32 * 64];   // [buf][hh][row][32k]
  __shared__ __align__(16) uint16_t Bs2[2][128 * 64];
  __shared__ float muS[32], rS[32], ckS[128], ekS[128];
  const int tid = threadIdx.x;
  const int bm = blockIdx.x * 32;
  const int wave = tid >> 6, lane = tid & 63;
  const int wx = wave & 1, wy = wave >> 1;
  const int col = lane & 15, quad = lane >> 4;
  const int csw = (col >> 1) & 3;
  const char* Abase = (const char*)Hb;
  const char* Bbase = (const char*)Wt2;

#define G2STAGE(k0v, bufv)                                                   \
  {                                                                          \
    {                                                                        \
      int off = tid * 16;                                                    \
      int hh = off >> 11, row = (off >> 6) & 31;                             \
      int sp = ((off >> 4) & 3) ^ ((row >> 1) & 3);                          \
      GLD16(Abase + ((size_t)(bm + row) * HID + (k0v) + hh * 32) * 2 +       \
                sp * 16,                                                     \
            (char*)&As2[bufv][0] + off);                                     \
    }                                                                        \
    _Pragma("unroll") for (int l = 0; l < 4; ++l) {                          \
      int off = tid * 16 + l * 4096;                                         \
      int hh = off >> 13, row = (off >> 6) & 127;                            \
      int sp = ((off >> 4) & 3) ^ ((row >> 1) & 3);                          \
      GLD16(Bbase + ((size_t)row * HID + (k0v) + hh * 32) * 2 + sp * 16,     \
            (char*)&Bs2[bufv][0] + off);                                     \
    }                                                                        \
  }

  G2STAGE(0, 0);
  if (tid < 32) {
    float s = sums[bm + tid], q = sums[NN + bm + tid];
    float mu = s * (1.0f / HID);
    float var = q * (1.0f / HID) - mu * mu;
    muS[tid] = mu;
    rS[tid] = rsqrtf(var + LN_EPS);
  }
  if (tid < 128) {
    float sc = 0.f, se = 0.f;
#pragma unroll 4
    for (int p = 0; p < 32; ++p) {
      sc += c_part[p * 128 + tid];
      se += c_part[4096 + p * 128 + tid];
    }
    ckS[tid] = sc;
    ekS[tid] = se + bd[tid];
  }
  f32x4 acc[4] = {};
  for (int it = 0; it < 16; ++it) {
    const int buf = it & 1;
    __syncthreads();
    if (it < 15) G2STAGE((it + 1) * 64, buf ^ 1);
#pragma unroll
    for (int hh = 0; hh < 2; ++hh) {
      bf16x8 a = *(const bf16x8*)&As2[buf][hh * 1024 + (wy * 16 + col) * 32 +
                                           (quad ^ csw) * 8];
#pragma unroll
      for (int nt = 0; nt < 4; ++nt) {
        bf16x8 b = *(const bf16x8*)&Bs2[buf][hh * 4096 +
                                             (wx * 64 + nt * 16 + col) * 32 +
                                             (quad ^ csw) * 8];
        acc[nt] =
            __builtin_amdgcn_mfma_f32_16x16x32_bf16(a, b, acc[nt], 0, 0, 0);
      }
    }
  }
#undef G2STAGE
#pragma unroll
  for (int nt = 0; nt < 4; ++nt) {
    int gj = wx * 64 + nt * 16 + col;
    float ck = ckS[gj], ek = ekS[gj];
#pragma unroll
    for (int r = 0; r < 4; ++r) {
      int li = wy * 16 + quad * 4 + r;
      float mu = muS[li], rr = rS[li];
      float z = fmaf(rr, acc[nt][r], fmaf(-rr * mu, ck, ek));
      Z[(size_t)(bm + li) * PROJ + gj] = f2bf(z);
    }
  }
}

// ------ flash logsumexp over Z Z^T: block-shared LDS j-tiles --------------
// grid (64, 32): chunk = 256 j -> 2048 blocks (~5 blocks/CU resident).
__device__ __forceinline__ void lse4(float& m, float& s, float v0, float v1,
                                     float v2, float v3) {
  float lm = fmaxf(fmaxf(v0, v1), fmaxf(v2, v3));
  float mn = fmaxf(m, lm);
  float tn = mn * CC;
  float rs = EXP2(fmaf(m, CC, -tn));
  float e = EXP2(fmaf(v0, CC, -tn)) + EXP2(fmaf(v1, CC, -tn)) +
            EXP2(fmaf(v2, CC, -tn)) + EXP2(fmaf(v3, CC, -tn));
  s = fmaf(s, rs, e);
  m = mn;
}

__global__ __launch_bounds__(256) void k_sim(const uint16_t* __restrict__ Z,
                                             float* __restrict__ m_part,
                                             float* __restrict__ s_part,
                                             float* __restrict__ pos_arr) {
  __shared__ __align__(16) uint16_t Bsh[2][64 * 128];
  const int tid = threadIdx.x;
  const int wave = tid >> 6, lane = tid & 63;
  const int col = lane & 15, quad = lane >> 4;
  const int wrow0 = blockIdx.x * 128 + wave * 32;
  const int chunk = blockIdx.y;
  const char* Zb = (const char*)Z;

  bf16x8 afr[2][4];
#pragma unroll
  for (int mt = 0; mt < 2; ++mt)
#pragma unroll
    for (int kc = 0; kc < 4; ++kc)
      afr[mt][kc] = *(const bf16x8*)(Z +
          (size_t)(wrow0 + mt * 16 + col) * PROJ + kc * 32 + quad * 8);

  float ms[8], ss[8];
#pragma unroll
  for (int i = 0; i < 8; ++i) { ms[i] = -INFINITY; ss[i] = 0.f; }

  const int diag_t = wrow0 & ~63;
  const int pos_t = ((wrow0 + NN / 2) & (NN - 1)) & ~63;
  const int jbase = chunk * 256;

#define STAGE(t, bufv)                                                      \
  {                                                                         \
    const int j0s = jbase + (t) * 64;                                       \
    _Pragma("unroll") for (int l = 0; l < 4; ++l) {                         \
      int off = tid * 16 + l * 4096;                                        \
      int row = off >> 8;                                                   \
      int p = (off >> 4) & 15;                                              \
      GLD16(Zb + (size_t)(j0s + row) * 256 + ((p ^ (row & 7)) << 4),        \
            (char*)&Bsh[bufv][0] + off);                                    \
    }                                                                       \
  }

  STAGE(0, 0);
  for (int t = 0; t < 4; ++t) {
    const int buf = t & 1;
    __syncthreads();
    if (t < 3) STAGE(t + 1, buf ^ 1);
    const int jt = jbase + t * 64;
    f32x4 acc[2][4] = {};
#pragma unroll
    for (int kc = 0; kc < 4; ++kc) {
      bf16x8 b[4];
#pragma unroll
      for (int nt = 0; nt < 4; ++nt) {
        int r = nt * 16 + col;
        b[nt] = *(const bf16x8*)&Bsh[buf][r * 128 +
                                          (((kc * 4 + quad) ^ (col & 7)) << 3)];
      }
#pragma unroll
      for (int mt = 0; mt < 2; ++mt)
#pragma unroll
        for (int nt = 0; nt < 4; ++nt)
          acc[mt][nt] = __builtin_amdgcn_mfma_f32_16x16x32_bf16(
              afr[mt][kc], b[nt], acc[mt][nt], 0, 0, 0);
    }
    if (jt != diag_t && jt != pos_t) {
#pragma unroll
      for (int mt = 0; mt < 2; ++mt)
#pragma unroll
        for (int r = 0; r < 4; ++r)
          lse4(ms[mt * 4 + r], ss[mt * 4 + r], acc[mt][0][r], acc[mt][1][r],
               acc[mt][2][r], acc[mt][3][r]);
    } else {
      const bool isd = (jt == diag_t);
#pragma unroll
      for (int mt = 0; mt < 2; ++mt)
#pragma unroll
        for (int r = 0; r < 4; ++r) {
          int gi = wrow0 + mt * 16 + quad * 4 + r;
          int partner = (gi + NN / 2) & (NN - 1);
          float v[4];
#pragma unroll
          for (int nt = 0; nt < 4; ++nt) {
            int gj = jt + nt * 16 + col;
            float d = acc[mt][nt][r];
            if (!isd && gj == partner) pos_arr[gi] = d;
            v[nt] = (isd && gj == gi) ? -INFINITY : d;
          }
          lse4(ms[mt * 4 + r], ss[mt * 4 + r], v[0], v[1], v[2], v[3]);
        }
    }
  }
#undef STAGE
#pragma unroll
  for (int ri = 0; ri < 8; ++ri) {
#pragma unroll
    for (int off = 1; off < 16; off <<= 1) {
      float om = __shfl_xor(ms[ri], off, 64);
      float os = __shfl_xor(ss[ri], off, 64);
      float mn = fmaxf(ms[ri], om);
      float tn = mn * CC;
      ss[ri] = fmaf(ss[ri], EXP2(fmaf(ms[ri], CC, -tn)),
                    os * EXP2(fmaf(om, CC, -tn)));
      ms[ri] = mn;
    }
  }
  if (col == 0) {
#pragma unroll
    for (int ri = 0; ri < 8; ++ri) {
      int gi = wrow0 + (ri >> 2) * 16 + quad * 4 + (ri & 3);
      m_part[(size_t)chunk * NN + gi] = ms[ri];
      s_part[(size_t)chunk * NN + gi] = ss[ri];
    }
  }
}

// ------- combine 32 chunk-partials per row + grid-wide mean (ticket) ------
__global__ __launch_bounds__(256) void k_combine(
    const float* __restrict__ m_part, const float* __restrict__ s_part,
    const float* __restrict__ pos_arr, float* __restrict__ accum,
    float* __restrict__ out) {
  const int tid = threadIdx.x;
  const int i = blockIdx.x * 256 + tid;
  float M = -INFINITY;
#pragma unroll
  for (int p = 0; p < 32; ++p) M = fmaxf(M, m_part[(size_t)p * NN + i]);
  float S = 0.f;
  float t = M * CC;
#pragma unroll
  for (int p = 0; p < 32; ++p)
    S += s_part[(size_t)p * NN + i] *
         EXP2(fmaf(m_part[(size_t)p * NN + i], CC, -t));
  float rl = (M - pos_arr[i]) * INV_T + logf(S);
#pragma unroll
  for (int off = 32; off > 0; off >>= 1) rl += __shfl_down(rl, off);
  __shared__ float red[4];
  const int wave = tid >> 6, lane = tid & 63;
  if (lane == 0) red[wave] = rl;
  __syncthreads();
  if (tid == 0) {
    float part = red[0] + red[1] + red[2] + red[3];
    atomicAdd(&accum[0], part);
    __threadfence();
    int old = atomicAdd((int*)&accum[1], 1);
    if (old == 31) {
      float tot = atomicAdd(&accum[0], 0.0f);  // atomic read-back
      out[0] = tot * (1.0f / NN);
    }
  }
}

extern "C" void kernel_launch(void* const* d_in, const int* in_sizes, int n_in,
                              void* d_out, int out_size, void* d_ws,
                              size_t ws_size, hipStream_t stream) {
  const float* x       = (const float*)d_in[0];
  const float* dense_w = (const float*)d_in[1];
  const float* dense_b = (const float*)d_in[2];
  const float* ln_g    = (const float*)d_in[3];
  const float* ln_b    = (const float*)d_in[4];
  const float* dec_w   = (const float*)d_in[5];
  const float* dec_b   = (const float*)d_in[6];
  float* out = (float*)d_out;
  char* ws = (char*)d_ws;
  // Phase 1 (through gemm1): xb [0,16M), wt [16M,18M), h [18M,34M)
  // Phase 2 (after gemm1):   z  [0,2M),  m_part/s_part reuse wt region
  uint16_t* xb      = (uint16_t*)(ws);
  uint16_t* wt      = (uint16_t*)(ws + 16777216);
  uint16_t* h       = (uint16_t*)(ws + 18874368);
  uint16_t* z       = (uint16_t*)(ws);
  float*    m_part  = (float*)(ws + 16777216);     // 32*8192*4 = 1 MiB
  float*    s_part  = (float*)(ws + 17825792);     // 1 MiB
  uint16_t* wt2     = (uint16_t*)(ws + 35651584);  // 256 KiB [128][1024]
  float*    sums    = (float*)(ws + 35913728);     // 64 KiB: sum|sumsq
  float*    c_part  = (float*)(ws + 35979264);     // 32 KiB: c[32][128]|e[32][128]
  float*    pos_arr = (float*)(ws + 36012032);     // 32 KiB
  float*    accum   = (float*)(ws + 36044800);     // 8 B: sum, ticket

  k_prep<<<dim3(9344), 256, 0, stream>>>(x, xb, dense_w, wt, dec_w, ln_g,
                                         ln_b, wt2, sums, c_part, accum);
  k_gemm1<<<dim3(64, 8), 256, 0, stream>>>(xb, wt, dense_b, h, sums);
  k_gemm2<<<dim3(NN / 32), 256, 0, stream>>>(h, wt2, dec_b, sums, c_part, z);
  k_sim<<<dim3(NN / 128, 32), 256, 0, stream>>>(z, m_part, s_part, pos_arr);
  k_combine<<<dim3(NN / 256), 256, 0, stream>>>(m_part, s_part, pos_arr,
                                                accum, out);
}

// Round 12
// 172.815 us; speedup vs baseline: 1.0525x; 1.0525x over previous
//
#include <hip/hip_runtime.h>
#include <math.h>
#include <stdint.h>

#define NN 8192
#define HID 1024
#define PROJ 128

constexpr float INV_T = 1.0f / 0.07f;
constexpr float LN_EPS = 1e-12f;
// exp((d-m)/T) = exp2((d-m)*CC)
constexpr float CC = 14.285714285714286f * 1.4426950408889634f;

typedef __bf16 bf16x8 __attribute__((ext_vector_type(8)));
typedef float f32x4 __attribute__((ext_vector_type(4)));

#define EXP2(x) __builtin_amdgcn_exp2f(x)

#define GLD16(g, l)                                                     \
  __builtin_amdgcn_global_load_lds(                                     \
      (const __attribute__((address_space(1))) uint32_t*)(g),           \
      (__attribute__((address_space(3))) uint32_t*)(l), 16, 0, 0)

__device__ __forceinline__ uint16_t f2bf(float f) {
  union { float f; uint32_t u; } c; c.f = f;
  uint32_t r = (c.u + 0x7FFFu + ((c.u >> 16) & 1u)) >> 16;
  return (uint16_t)r;
}

// gelu(v) ~= v * sigmoid(2u), u = 0.79788456(v + 0.044715 v^3)
__device__ __forceinline__ float gelu_f(float v) {
  float w = v * v;
  float u = v * fmaf(w, 0.0356774081f, 0.7978845608f);
  float e = EXP2(u * -2.8853900818f);
  return v * __builtin_amdgcn_rcpf(1.0f + e);
}

// ---- k_prep: fused conv(x->bf16) + t1(dense_w^T) + t2(dec_w^T * gamma) ----
__global__ __launch_bounds__(256) void k_prep(
    const float* __restrict__ x, uint16_t* __restrict__ xb,
    const float* __restrict__ dw, uint16_t* __restrict__ wt,
    const float* __restrict__ decw, const float* __restrict__ gamma,
    const float* __restrict__ beta, uint16_t* __restrict__ wt2,
    float* __restrict__ sums, float* __restrict__ c_part,
    float* __restrict__ accum) {
  __shared__ __align__(16) char sm[8448];
  const int b = blockIdx.x, t = threadIdx.x;
  if (b < 8192) {
    if (b < 64) sums[b * 256 + t] = 0.f;            // sum[8192]|sumsq[8192]
    else if (b == 64 && t < 2) accum[t] = 0.f;      // accum, ticket
    int i = (b * 256 + t) * 4;
    float4 v = *(const float4*)(x + i);
    ushort4 o;
    o.x = f2bf(v.x); o.y = f2bf(v.y); o.z = f2bf(v.z); o.w = f2bf(v.w);
    *(ushort4*)(xb + i) = o;
  } else if (b < 9216) {
    uint16_t (*tt)[33] = (uint16_t(*)[33])sm;
    const int lb = b - 8192;
    const int cb = (lb & 31) * 32, rb = (lb >> 5) * 32;
    const int tr = t >> 3, tc4 = (t & 7) * 4;
    float4 v = *(const float4*)(dw + (size_t)(rb + tr) * HID + cb + tc4);
    tt[tc4 + 0][tr] = f2bf(v.x);
    tt[tc4 + 1][tr] = f2bf(v.y);
    tt[tc4 + 2][tr] = f2bf(v.z);
    tt[tc4 + 3][tr] = f2bf(v.w);
    __syncthreads();
    const int oc = t >> 3, or4 = (t & 7) * 4;
    ushort4 o;
    o.x = tt[oc][or4 + 0]; o.y = tt[oc][or4 + 1];
    o.z = tt[oc][or4 + 2]; o.w = tt[oc][or4 + 3];
    *(ushort4*)(wt + (size_t)(cb + oc) * HID + rb + or4) = o;
  } else {
    float (*tg)[33] = (float(*)[33])sm;
    float (*tb)[33] = (float(*)[33])(sm + 4224);
    const int lb = b - 9216;
    const int cb = (lb & 3) * 32, rb = (lb >> 2) * 32;
    const int tr = t >> 3, tc4 = (t & 7) * 4;
    const float g = gamma[rb + tr], be = beta[rb + tr];
    float4 v = *(const float4*)(decw + (size_t)(rb + tr) * PROJ + cb + tc4);
    tg[tc4 + 0][tr] = g * v.x;  tb[tc4 + 0][tr] = be * v.x;
    tg[tc4 + 1][tr] = g * v.y;  tb[tc4 + 1][tr] = be * v.y;
    tg[tc4 + 2][tr] = g * v.z;  tb[tc4 + 2][tr] = be * v.z;
    tg[tc4 + 3][tr] = g * v.w;  tb[tc4 + 3][tr] = be * v.w;
    __syncthreads();
    const int oc = t >> 3, or4 = (t & 7) * 4;
    ushort4 o;
    o.x = f2bf(tg[oc][or4 + 0]); o.y = f2bf(tg[oc][or4 + 1]);
    o.z = f2bf(tg[oc][or4 + 2]); o.w = f2bf(tg[oc][or4 + 3]);
    *(ushort4*)(wt2 + (size_t)(cb + oc) * HID + rb + or4) = o;
    if (t < 32) {
      float sc = 0.f, se = 0.f;
#pragma unroll
      for (int d = 0; d < 32; ++d) { sc += tg[t][d]; se += tb[t][d]; }
      c_part[(rb >> 5) * 128 + cb + t] = sc;            // c partial
      c_part[4096 + (rb >> 5) * 128 + cb + t] = se;     // e partial
    }
  }
}

// -------- GEMM1: h = gelu(x@W+b) bf16, + per-row sum/sumsq atomics --------
// m97 geometry: 128x128 tile, BK=32, wave-tile 64x64, dbuf single-barrier,
// source-side XOR swizzle (conflict-free). __launch_bounds__(256,4) caps
// VGPR at 128 -> 4 blocks/CU resident (16 waves/CU) for latency hiding.
// grid (64, 8): linear%8 = bm%8 -> bn-blocks of one bm share an XCD.
__global__ __launch_bounds__(256, 4) void k_gemm1(
    const uint16_t* __restrict__ Ab, const uint16_t* __restrict__ Bt,
    const float* __restrict__ bias, uint16_t* __restrict__ Hout,
    float* __restrict__ sums) {
  __shared__ __align__(16) uint16_t As[2][128 * 32];
  __shared__ __align__(16) uint16_t Bs[2][128 * 32];
  const int tid = threadIdx.x;
  const int bm = blockIdx.x * 128, bn = blockIdx.y * 128;
  const int wave = tid >> 6, lane = tid & 63;
  const int wx = wave & 1, wy = wave >> 1;
  const int col = lane & 15, quad = lane >> 4;
  const int csw = (col >> 1) & 3;   // read-side chunk swizzle
  f32x4 acc[4][4] = {};
  const char* Abase = (const char*)Ab;
  const char* Bbase = (const char*)Bt;

#define G1STAGE(k0v, bufv)                                                   \
  {                                                                          \
    _Pragma("unroll") for (int l = 0; l < 2; ++l) {                          \
      int off = tid * 16 + l * 4096;                                         \
      int row = off >> 6;                                                    \
      int sp = ((off >> 4) & 3) ^ ((row >> 1) & 3);                          \
      GLD16(Abase + ((size_t)(bm + row) * HID + (k0v)) * 2 + sp * 16,        \
            (char*)&As[bufv][0] + off);                                      \
    }                                                                        \
    _Pragma("unroll") for (int l = 0; l < 2; ++l) {                          \
      int off = tid * 16 + l * 4096;                                         \
      int row = off >> 6;                                                    \
      int sp = ((off >> 4) & 3) ^ ((row >> 1) & 3);                          \
      GLD16(Bbase + ((size_t)(bn + row) * HID + (k0v)) * 2 + sp * 16,        \
            (char*)&Bs[bufv][0] + off);                                      \
    }                                                                        \
  }

  G1STAGE(0, 0);
  for (int it = 0; it < 32; ++it) {
    const int buf = it & 1;
    __syncthreads();           // staging for panel `it` landed
    if (it < 31) G1STAGE((it + 1) * 32, buf ^ 1);
    bf16x8 a[4], b[4];
#pragma unroll
    for (int mt = 0; mt < 4; ++mt)
      a[mt] = *(const bf16x8*)&As[buf][(wy * 64 + mt * 16 + col) * 32 +
                                       (quad ^ csw) * 8];
#pragma unroll
    for (int nt = 0; nt < 4; ++nt)
      b[nt] = *(const bf16x8*)&Bs[buf][(wx * 64 + nt * 16 + col) * 32 +
                                       (quad ^ csw) * 8];
#pragma unroll
    for (int mt = 0; mt < 4; ++mt)
#pragma unroll
      for (int nt = 0; nt < 4; ++nt)
        acc[mt][nt] = __builtin_amdgcn_mfma_f32_16x16x32_bf16(
            a[mt], b[nt], acc[mt][nt], 0, 0, 0);
  }
#undef G1STAGE
  float rsum[4][4] = {}, rsq[4][4] = {};
#pragma unroll
  for (int nt = 0; nt < 4; ++nt) {
    int gj = bn + wx * 64 + nt * 16 + col;
    float bv = bias[gj];
#pragma unroll
    for (int mt = 0; mt < 4; ++mt)
#pragma unroll
      for (int r = 0; r < 4; ++r) {
        int gi = bm + wy * 64 + mt * 16 + quad * 4 + r;
        float gl = gelu_f(acc[mt][nt][r] + bv);
        Hout[(size_t)gi * HID + gj] = f2bf(gl);
        rsum[mt][r] += gl;
        rsq[mt][r] = fmaf(gl, gl, rsq[mt][r]);
      }
  }
#pragma unroll
  for (int mt = 0; mt < 4; ++mt)
#pragma unroll
    for (int r = 0; r < 4; ++r) {
      float s1 = rsum[mt][r], s2 = rsq[mt][r];
#pragma unroll
      for (int off = 1; off < 16; off <<= 1) {
        s1 += __shfl_xor(s1, off, 64);
        s2 += __shfl_xor(s2, off, 64);
      }
      if (col == 0) {
        int gi = bm + wy * 64 + mt * 16 + quad * 4 + r;
        atomicAdd(&sums[gi], s1);
        atomicAdd(&sums[NN + gi], s2);
      }
    }
}

// --- GEMM2 with LN folded: z = r*(h@Wg) - r*mu*c + e + dec_b, bf16 out ----
// 32x128 tile, BK=32, dbuf single-barrier, same XOR swizzle.
__global__ __launch_bounds__(256) void k_gemm2(
    const uint16_t* __restrict__ Hb, const uint16_t* __restrict__ Wt2,
    const float* __restrict__ bd, const float* __restrict__ sums,
    const float* __restrict__ c_part, uint16_t* __restrict__ Z) {
  __shared__ __align__(16) uint16_t As2[2][32 * 32];
  __shared__ __align__(16) uint16_t Bs2[2][128 * 32];
  __shared__ float muS[32], rS[32], ckS[128], ekS[128];
  const int tid = threadIdx.x;
  const int bm = blockIdx.x * 32;
  const int wave = tid >> 6, lane = tid & 63;
  const int wx = wave & 1, wy = wave >> 1;
  const int col = lane & 15, quad = lane >> 4;
  const int csw = (col >> 1) & 3;
  const char* Abase = (const char*)Hb;
  const char* Bbase = (const char*)Wt2;

#define G2STAGE(k0v, bufv)                                                   \
  {                                                                          \
    if (tid < 128) {                                                         \
      int off = tid * 16;                                                    \
      int row = off >> 6;                                                    \
      int sp = ((off >> 4) & 3) ^ ((row >> 1) & 3);                          \
      GLD16(Abase + ((size_t)(bm + row) * HID + (k0v)) * 2 + sp * 16,        \
            (char*)&As2[bufv][0] + off);                                     \
    }                                                                        \
    _Pragma("unroll") for (int l = 0; l < 2; ++l) {                          \
      int off = tid * 16 + l * 4096;                                         \
      int row = off >> 6;                                                    \
      int sp = ((off >> 4) & 3) ^ ((row >> 1) & 3);                          \
      GLD16(Bbase + ((size_t)row * HID + (k0v)) * 2 + sp * 16,               \
            (char*)&Bs2[bufv][0] + off);                                     \
    }                                                                        \
  }

  G2STAGE(0, 0);
  if (tid < 32) {
    float s = sums[bm + tid], q = sums[NN + bm + tid];
    float mu = s * (1.0f / HID);
    float var = q * (1.0f / HID) - mu * mu;
    muS[tid] = mu;
    rS[tid] = rsqrtf(var + LN_EPS);
  }
  if (tid < 128) {
    float sc = 0.f, se = 0.f;
#pragma unroll 4
    for (int p = 0; p < 32; ++p) {
      sc += c_part[p * 128 + tid];
      se += c_part[4096 + p * 128 + tid];
    }
    ckS[tid] = sc;
    ekS[tid] = se + bd[tid];
  }
  f32x4 acc[4] = {};
  for (int it = 0; it < 32; ++it) {
    const int buf = it & 1;
    __syncthreads();
    if (it < 31) G2STAGE((it + 1) * 32, buf ^ 1);
    bf16x8 a =
        *(const bf16x8*)&As2[buf][(wy * 16 + col) * 32 + (quad ^ csw) * 8];
#pragma unroll
    for (int nt = 0; nt < 4; ++nt) {
      bf16x8 b = *(const bf16x8*)&Bs2[buf][(wx * 64 + nt * 16 + col) * 32 +
                                           (quad ^ csw) * 8];
      acc[nt] = __builtin_amdgcn_mfma_f32_16x16x32_bf16(a, b, acc[nt], 0, 0, 0);
    }
  }
#undef G2STAGE
#pragma unroll
  for (int nt = 0; nt < 4; ++nt) {
    int gj = wx * 64 + nt * 16 + col;
    float ck = ckS[gj], ek = ekS[gj];
#pragma unroll
    for (int r = 0; r < 4; ++r) {
      int li = wy * 16 + quad * 4 + r;
      float mu = muS[li], rr = rS[li];
      float z = fmaf(rr, acc[nt][r], fmaf(-rr * mu, ck, ek));
      Z[(size_t)(bm + li) * PROJ + gj] = f2bf(z);
    }
  }
}

// ------ flash logsumexp over Z Z^T: block-shared LDS j-tiles --------------
__device__ __forceinline__ void lse4(float& m, float& s, float v0, float v1,
                                     float v2, float v3) {
  float lm = fmaxf(fmaxf(v0, v1), fmaxf(v2, v3));
  float mn = fmaxf(m, lm);
  float tn = mn * CC;
  float rs = EXP2(fmaf(m, CC, -tn));
  float e = EXP2(fmaf(v0, CC, -tn)) + EXP2(fmaf(v1, CC, -tn)) +
            EXP2(fmaf(v2, CC, -tn)) + EXP2(fmaf(v3, CC, -tn));
  s = fmaf(s, rs, e);
  m = mn;
}

__global__ __launch_bounds__(256) void k_sim(const uint16_t* __restrict__ Z,
                                             float* __restrict__ m_part,
                                             float* __restrict__ s_part,
                                             float* __restrict__ pos_arr) {
  __shared__ __align__(16) uint16_t Bsh[2][64 * 128];
  const int tid = threadIdx.x;
  const int wave = tid >> 6, lane = tid & 63;
  const int col = lane & 15, quad = lane >> 4;
  const int wrow0 = blockIdx.x * 128 + wave * 32;
  const int chunk = blockIdx.y;
  const char* Zb = (const char*)Z;

  bf16x8 afr[2][4];
#pragma unroll
  for (int mt = 0; mt < 2; ++mt)
#pragma unroll
    for (int kc = 0; kc < 4; ++kc)
      afr[mt][kc] = *(const bf16x8*)(Z +
          (size_t)(wrow0 + mt * 16 + col) * PROJ + kc * 32 + quad * 8);

  float ms[8], ss[8];
#pragma unroll
  for (int i = 0; i < 8; ++i) { ms[i] = -INFINITY; ss[i] = 0.f; }

  const int diag_t = wrow0 & ~63;
  const int pos_t = ((wrow0 + NN / 2) & (NN - 1)) & ~63;
  const int jbase = chunk * 512;

#define STAGE(t, bufv)                                                      \
  {                                                                         \
    const int j0s = jbase + (t) * 64;                                       \
    _Pragma("unroll") for (int l = 0; l < 4; ++l) {                         \
      int off = tid * 16 + l * 4096;                                        \
      int row = off >> 8;                                                   \
      int p = (off >> 4) & 15;                                              \
      GLD16(Zb + (size_t)(j0s + row) * 256 + ((p ^ (row & 7)) << 4),        \
            (char*)&Bsh[bufv][0] + off);                                    \
    }                                                                       \
  }

  STAGE(0, 0);
  for (int t = 0; t < 8; ++t) {
    const int buf = t & 1;
    __syncthreads();
    if (t < 7) STAGE(t + 1, buf ^ 1);
    const int jt = jbase + t * 64;
    f32x4 acc[2][4] = {};
#pragma unroll
    for (int kc = 0; kc < 4; ++kc) {
      bf16x8 b[4];
#pragma unroll
      for (int nt = 0; nt < 4; ++nt) {
        int r = nt * 16 + col;
        b[nt] = *(const bf16x8*)&Bsh[buf][r * 128 +
                                          (((kc * 4 + quad) ^ (col & 7)) << 3)];
      }
#pragma unroll
      for (int mt = 0; mt < 2; ++mt)
#pragma unroll
        for (int nt = 0; nt < 4; ++nt)
          acc[mt][nt] = __builtin_amdgcn_mfma_f32_16x16x32_bf16(
              afr[mt][kc], b[nt], acc[mt][nt], 0, 0, 0);
    }
    if (jt != diag_t && jt != pos_t) {
#pragma unroll
      for (int mt = 0; mt < 2; ++mt)
#pragma unroll
        for (int r = 0; r < 4; ++r)
          lse4(ms[mt * 4 + r], ss[mt * 4 + r], acc[mt][0][r], acc[mt][1][r],
               acc[mt][2][r], acc[mt][3][r]);
    } else {
      const bool isd = (jt == diag_t);
#pragma unroll
      for (int mt = 0; mt < 2; ++mt)
#pragma unroll
        for (int r = 0; r < 4; ++r) {
          int gi = wrow0 + mt * 16 + quad * 4 + r;
          int partner = (gi + NN / 2) & (NN - 1);
          float v[4];
#pragma unroll
          for (int nt = 0; nt < 4; ++nt) {
            int gj = jt + nt * 16 + col;
            float d = acc[mt][nt][r];
            if (!isd && gj == partner) pos_arr[gi] = d;
            v[nt] = (isd && gj == gi) ? -INFINITY : d;
          }
          lse4(ms[mt * 4 + r], ss[mt * 4 + r], v[0], v[1], v[2], v[3]);
        }
    }
  }
#undef STAGE
#pragma unroll
  for (int ri = 0; ri < 8; ++ri) {
#pragma unroll
    for (int off = 1; off < 16; off <<= 1) {
      float om = __shfl_xor(ms[ri], off, 64);
      float os = __shfl_xor(ss[ri], off, 64);
      float mn = fmaxf(ms[ri], om);
      float tn = mn * CC;
      ss[ri] = fmaf(ss[ri], EXP2(fmaf(ms[ri], CC, -tn)),
                    os * EXP2(fmaf(om, CC, -tn)));
      ms[ri] = mn;
    }
  }
  if (col == 0) {
#pragma unroll
    for (int ri = 0; ri < 8; ++ri) {
      int gi = wrow0 + (ri >> 2) * 16 + quad * 4 + (ri & 3);
      m_part[(size_t)chunk * NN + gi] = ms[ri];
      s_part[(size_t)chunk * NN + gi] = ss[ri];
    }
  }
}

// ------- combine 16 chunk-partials per row + grid-wide mean (ticket) ------
__global__ __launch_bounds__(256) void k_combine(
    const float* __restrict__ m_part, const float* __restrict__ s_part,
    const float* __restrict__ pos_arr, float* __restrict__ accum,
    float* __restrict__ out) {
  const int tid = threadIdx.x;
  const int i = blockIdx.x * 256 + tid;
  float M = -INFINITY;
#pragma unroll
  for (int p = 0; p < 16; ++p) M = fmaxf(M, m_part[(size_t)p * NN + i]);
  float S = 0.f;
  float t = M * CC;
#pragma unroll
  for (int p = 0; p < 16; ++p)
    S += s_part[(size_t)p * NN + i] *
         EXP2(fmaf(m_part[(size_t)p * NN + i], CC, -t));
  float rl = (M - pos_arr[i]) * INV_T + logf(S);
#pragma unroll
  for (int off = 32; off > 0; off >>= 1) rl += __shfl_down(rl, off);
  __shared__ float red[4];
  const int wave = tid >> 6, lane = tid & 63;
  if (lane == 0) red[wave] = rl;
  __syncthreads();
  if (tid == 0) {
    float part = red[0] + red[1] + red[2] + red[3];
    atomicAdd(&accum[0], part);
    __threadfence();
    int old = atomicAdd((int*)&accum[1], 1);
    if (old == 31) {
      float tot = atomicAdd(&accum[0], 0.0f);  // atomic read-back
      out[0] = tot * (1.0f / NN);
    }
  }
}

extern "C" void kernel_launch(void* const* d_in, const int* in_sizes, int n_in,
                              void* d_out, int out_size, void* d_ws,
                              size_t ws_size, hipStream_t stream) {
  const float* x       = (const float*)d_in[0];
  const float* dense_w = (const float*)d_in[1];
  const float* dense_b = (const float*)d_in[2];
  const float* ln_g    = (const float*)d_in[3];
  const float* ln_b    = (const float*)d_in[4];
  const float* dec_w   = (const float*)d_in[5];
  const float* dec_b   = (const float*)d_in[6];
  float* out = (float*)d_out;
  char* ws = (char*)d_ws;
  // Phase 1 (through gemm1): xb [0,16M), wt [16M,18M), h [18M,34M)
  // Phase 2 (after gemm1):   z  [0,2M),  m_part/s_part reuse wt region
  uint16_t* xb      = (uint16_t*)(ws);
  uint16_t* wt      = (uint16_t*)(ws + 16777216);
  uint16_t* h       = (uint16_t*)(ws + 18874368);
  uint16_t* z       = (uint16_t*)(ws);
  float*    m_part  = (float*)(ws + 16777216);     // 16*8192*4 = 512 KiB
  float*    s_part  = (float*)(ws + 17301504);     // 512 KiB
  uint16_t* wt2     = (uint16_t*)(ws + 35651584);  // 256 KiB [128][1024]
  float*    sums    = (float*)(ws + 35913728);     // 64 KiB: sum|sumsq
  float*    c_part  = (float*)(ws + 35979264);     // 32 KiB: c[32][128]|e[32][128]
  float*    pos_arr = (float*)(ws + 36012032);     // 32 KiB
  float*    accum   = (float*)(ws + 36044800);     // 8 B: sum, ticket

  k_prep<<<dim3(9344), 256, 0, stream>>>(x, xb, dense_w, wt, dec_w, ln_g,
                                         ln_b, wt2, sums, c_part, accum);
  k_gemm1<<<dim3(64, 8), 256, 0, stream>>>(xb, wt, dense_b, h, sums);
  k_gemm2<<<dim3(NN / 32), 256, 0, stream>>>(h, wt2, dec_b, sums, c_part, z);
  k_sim<<<dim3(NN / 128, 16), 256, 0, stream>>>(z, m_part, s_part, pos_arr);
  k_combine<<<dim3(NN / 256), 256, 0, stream>>>(m_part, s_part, pos_arr,
                                                accum, out);
}